// Round 5
// baseline (135.901 us; speedup 1.0000x reference)
//
#include <hip/hip_runtime.h>

#define EPS 1e-7f
#define NB 64
#define NI 1152
#define NJ 8
#define NK 43
#define NL 16
#define NSLICE 4
#define SLICE 288            // NI / NSLICE
#define THREADS 384
#define NKG 11               // groups of 4 k's (44 = NK+1 pad)
#define CPS 292              // float4 row stride for cP (288 + 4 pad)
#define GPS 33               // float row stride for Gp (odd -> conflict-free)
#define PARTS 352            // padded stride for G partials in ws
#define SPIN_LIMIT 100000000u

__global__ __launch_bounds__(THREADS, 1)
void capsule_routing_kernel(const float* __restrict__ X, const float* __restrict__ W,
                            float* __restrict__ out, int* __restrict__ cnt,
                            float* __restrict__ part) {
    __shared__ __align__(16) float sW[NJ*NK*NL];       // 22,016 B
    __shared__ __align__(16) float sX[SLICE*NJ];       //  9,216 B (this block's i-slice)
    __shared__ __align__(16) float uMem[NKG*CPS*4];    // 51,392 B: cP / Gp / xs scratch
    __shared__ __align__(16) float sWv[NJ][44];
    __shared__ float sS[NK][NL];
    __shared__ float sV[NK][NL];
    __shared__ float sG[NK*NJ];
    __shared__ float sXs[NJ];

    float4* cP  = (float4*)uMem;    // [NKG][CPS]
    float*  Gp  = uMem;             // [352][GPS]
    float*  xsP = uMem;             // [NJ][48] prologue scratch

    const int tid = threadIdx.x;
    const int b  = blockIdx.x >> 2;
    const int sl = blockIdx.x & 3;
    const float* Xb = X + (size_t)b * (NI*NJ);
    float4* sX4 = (float4*)sX;

    // ---- load W into LDS ----
    {
        const float4* W4 = (const float4*)W;
        float4* sW4 = (float4*)sW;
        for (int t = tid; t < (NJ*NK*NL)/4; t += THREADS) sW4[t] = W4[t];
    }
    // ---- load this block's X slice into LDS ----
    {
        const float4* Xs4 = (const float4*)(Xb + (size_t)sl*SLICE*NJ);
        for (int t = tid; t < SLICE*NJ/4; t += THREADS) sX4[t] = Xs4[t];
    }
    // ---- xs[j] = sum over ALL i of x[i][j] (redundant per block) ----
    {
        const int j = tid / 48, sub = tid % 48;
        float p = 0.f;
        #pragma unroll
        for (int ii = 0; ii < NI/48; ++ii) p += Xb[(sub + 48*ii)*NJ + j];
        xsP[j*48 + sub] = p;
    }
    __syncthreads();
    if (tid < NJ) {
        float s = 0.f;
        for (int q = 0; q < 48; ++q) s += xsP[tid*48 + q];
        sXs[tid] = s;
    }
    __syncthreads();
    // ---- s0 = (1/43) * xs . W ----
    for (int t = tid; t < NK*NL; t += THREADS) {
        float s = 0.f;
        #pragma unroll
        for (int j = 0; j < NJ; ++j) s += sXs[j] * sW[j*NK*NL + t];
        sS[t >> 4][t & 15] = s * (1.0f/43.0f);
    }
    __syncthreads();
    // ---- squash -> v0 ----
    if (tid < NK) {
        float s2 = 0.f;
        #pragma unroll
        for (int l = 0; l < NL; ++l) { float v = sS[tid][l]; s2 += v*v; }
        float scale = s2 / ((1.f + s2) * sqrtf(s2 + EPS));
        #pragma unroll
        for (int l = 0; l < NL; ++l) sV[tid][l] = scale * sS[tid][l];
    }
    if (tid < NJ) sWv[tid][43] = 0.f;
    __syncthreads();
    // ---- Wv0[j,k] ----
    if (tid < 352) {
        const int j = tid / 44, k = tid % 44;
        if (k < NK) {
            float wv = 0.f;
            #pragma unroll
            for (int l = 0; l < NL; ++l) wv += sW[j*NK*NL + k*NL + l] * sV[k][l];
            sWv[j][k] = wv;
        }
    }
    __syncthreads();

    // ---- routing passes ----
    for (int pass = 0; pass < 2; ++pass) {
        float acc[4][8];
        #pragma unroll
        for (int q = 0; q < 4; ++q)
            #pragma unroll
            for (int j = 0; j < 8; ++j) acc[q][j] = 0.f;

        // ---- Phase A: logits + softmax for this slice's 288 i's ----
        float a[44];
        if (tid < SLICE) {
            float4 x0 = sX4[tid*2], x1 = sX4[tid*2 + 1];
            float xr[NJ] = {x0.x, x0.y, x0.z, x0.w, x1.x, x1.y, x1.z, x1.w};
            #pragma unroll
            for (int k = 0; k < 44; ++k) a[k] = 0.f;
            #pragma unroll
            for (int j = 0; j < NJ; ++j) {
                #pragma unroll
                for (int k4 = 0; k4 < 11; ++k4) {
                    float4 wv = *(const float4*)&sWv[j][k4*4];
                    a[k4*4+0] = fmaf(xr[j], wv.x, a[k4*4+0]);
                    a[k4*4+1] = fmaf(xr[j], wv.y, a[k4*4+1]);
                    a[k4*4+2] = fmaf(xr[j], wv.z, a[k4*4+2]);
                    a[k4*4+3] = fmaf(xr[j], wv.w, a[k4*4+3]);
                }
            }
            float m0=a[0], m1=a[1], m2=a[2], m3=a[3];
            #pragma unroll
            for (int k = 4; k < 40; k += 4) {
                m0 = fmaxf(m0, a[k+0]); m1 = fmaxf(m1, a[k+1]);
                m2 = fmaxf(m2, a[k+2]); m3 = fmaxf(m3, a[k+3]);
            }
            m0 = fmaxf(m0, a[40]); m1 = fmaxf(m1, a[41]); m2 = fmaxf(m2, a[42]);
            const float m = fmaxf(fmaxf(m0, m1), fmaxf(m2, m3));
            float z0=0.f, z1=0.f, z2=0.f, z3=0.f;
            #pragma unroll
            for (int k = 0; k < 40; k += 4) {
                a[k+0] = __expf(a[k+0]-m); z0 += a[k+0];
                a[k+1] = __expf(a[k+1]-m); z1 += a[k+1];
                a[k+2] = __expf(a[k+2]-m); z2 += a[k+2];
                a[k+3] = __expf(a[k+3]-m); z3 += a[k+3];
            }
            a[40] = __expf(a[40]-m); z0 += a[40];
            a[41] = __expf(a[41]-m); z1 += a[41];
            a[42] = __expf(a[42]-m); z2 += a[42];
            const float inv = 1.f / ((z0+z1) + (z2+z3));
            #pragma unroll
            for (int k = 0; k < NK; ++k) a[k] *= inv;
            a[43] = 0.f;
        }
        __syncthreads();   // uMem free (prologue scratch / previous pass Gp reads done)
        if (tid < SLICE) {
            #pragma unroll
            for (int kg = 0; kg < NKG; ++kg)
                cP[kg*CPS + tid] = make_float4(a[4*kg], a[4*kg+1], a[4*kg+2], a[4*kg+3]);
        }
        __syncthreads();   // cP ready
        // ---- Phase B: register-blocked G over slice (352 threads, 9 iters) ----
        if (tid < 352) {
            const int kg = tid >> 5, s = tid & 31;
            #pragma unroll
            for (int ii = 0; ii < SLICE/32; ++ii) {
                const int il = s + 32*ii;
                float4 c4 = cP[kg*CPS + il];
                float4 xa = sX4[il*2], xb = sX4[il*2 + 1];
                acc[0][0]=fmaf(c4.x,xa.x,acc[0][0]); acc[0][1]=fmaf(c4.x,xa.y,acc[0][1]);
                acc[0][2]=fmaf(c4.x,xa.z,acc[0][2]); acc[0][3]=fmaf(c4.x,xa.w,acc[0][3]);
                acc[0][4]=fmaf(c4.x,xb.x,acc[0][4]); acc[0][5]=fmaf(c4.x,xb.y,acc[0][5]);
                acc[0][6]=fmaf(c4.x,xb.z,acc[0][6]); acc[0][7]=fmaf(c4.x,xb.w,acc[0][7]);
                acc[1][0]=fmaf(c4.y,xa.x,acc[1][0]); acc[1][1]=fmaf(c4.y,xa.y,acc[1][1]);
                acc[1][2]=fmaf(c4.y,xa.z,acc[1][2]); acc[1][3]=fmaf(c4.y,xa.w,acc[1][3]);
                acc[1][4]=fmaf(c4.y,xb.x,acc[1][4]); acc[1][5]=fmaf(c4.y,xb.y,acc[1][5]);
                acc[1][6]=fmaf(c4.y,xb.z,acc[1][6]); acc[1][7]=fmaf(c4.y,xb.w,acc[1][7]);
                acc[2][0]=fmaf(c4.z,xa.x,acc[2][0]); acc[2][1]=fmaf(c4.z,xa.y,acc[2][1]);
                acc[2][2]=fmaf(c4.z,xa.z,acc[2][2]); acc[2][3]=fmaf(c4.z,xa.w,acc[2][3]);
                acc[2][4]=fmaf(c4.z,xb.x,acc[2][4]); acc[2][5]=fmaf(c4.z,xb.y,acc[2][5]);
                acc[2][6]=fmaf(c4.z,xb.z,acc[2][6]); acc[2][7]=fmaf(c4.z,xb.w,acc[2][7]);
                acc[3][0]=fmaf(c4.w,xa.x,acc[3][0]); acc[3][1]=fmaf(c4.w,xa.y,acc[3][1]);
                acc[3][2]=fmaf(c4.w,xa.z,acc[3][2]); acc[3][3]=fmaf(c4.w,xa.w,acc[3][3]);
                acc[3][4]=fmaf(c4.w,xb.x,acc[3][4]); acc[3][5]=fmaf(c4.w,xb.y,acc[3][5]);
                acc[3][6]=fmaf(c4.w,xb.z,acc[3][6]); acc[3][7]=fmaf(c4.w,xb.w,acc[3][7]);
            }
        }
        __syncthreads();   // cP reads done -> alias as Gp
        if (tid < 352) {
            #pragma unroll
            for (int q = 0; q < 4; ++q)
                #pragma unroll
                for (int j = 0; j < 8; ++j)
                    Gp[tid*GPS + q*8 + j] = acc[q][j];
        }
        __syncthreads();
        // ---- reduce 32 lanes -> G partial for this slice -> global ws ----
        if (tid < NK*NJ) {
            const int k = tid >> 3, j = tid & 7;
            const int kg = k >> 2, k4 = k & 3;
            float g = 0.f;
            for (int s = 0; s < 32; ++s) g += Gp[(kg*32 + s)*GPS + k4*8 + j];
            part[((size_t)(pass*NB + b)*NSLICE + sl)*PARTS + tid] = g;
        }
        __threadfence();   // each thread: own stores visible at device scope
        __syncthreads();   // all threads' fences done
        // ---- rendezvous: 4 slices of batch b ----
        {
            const int cidx = pass*NB + b;
            if (tid == 0) {
                __hip_atomic_fetch_add(&cnt[cidx], 1, __ATOMIC_RELEASE, __HIP_MEMORY_SCOPE_AGENT);
                if (pass == 0 || sl == 0) {   // only readers spin
                    unsigned spins = 0;
                    while (__hip_atomic_load(&cnt[cidx], __ATOMIC_ACQUIRE,
                                             __HIP_MEMORY_SCOPE_AGENT) < NSLICE
                           && ++spins < SPIN_LIMIT)
                        __builtin_amdgcn_s_sleep(1);
                }
            }
            __syncthreads();
            __threadfence();   // acquire: see partners' partials
        }
        // ---- tail: reduce partials -> s -> squash (pass0: all; pass1: slice 0) ----
        if (pass == 0 || sl == 0) {
            if (tid < NK*NJ) {
                const float* pb = part + (size_t)(pass*NB + b)*NSLICE*PARTS;
                float g = 0.f;
                #pragma unroll
                for (int q = 0; q < NSLICE; ++q) g += pb[q*PARTS + tid];
                sG[tid] = g;
            }
            __syncthreads();
            for (int t = tid; t < NK*NL; t += THREADS) {
                const int k = t >> 4;
                float s = 0.f;
                #pragma unroll
                for (int j = 0; j < NJ; ++j) s = fmaf(sG[k*8+j], sW[j*NK*NL + t], s);
                sS[k][t & 15] = s;
            }
            __syncthreads();
            if (tid < NK) {
                float s2 = 0.f;
                #pragma unroll
                for (int l = 0; l < NL; ++l) { float v = sS[tid][l]; s2 += v*v; }
                float scale = s2 / ((1.f + s2) * sqrtf(s2 + EPS));
                #pragma unroll
                for (int l = 0; l < NL; ++l) sV[tid][l] = scale * sS[tid][l];
            }
            __syncthreads();
            if (pass == 0) {
                if (tid < 352) {
                    const int j = tid / 44, k = tid % 44;
                    if (k < NK) {
                        float wv = 0.f;
                        #pragma unroll
                        for (int l = 0; l < NL; ++l) wv += sW[j*NK*NL + k*NL + l] * sV[k][l];
                        sWv[j][k] += wv;
                    }
                }
            } else {
                for (int t = tid; t < NK*NL; t += THREADS)
                    out[(size_t)b*NK*NL + t] = sV[t >> 4][t & 15];
            }
        }
        __syncthreads();   // sWv stable before next pass's Phase A
    }
}

extern "C" void kernel_launch(void* const* d_in, const int* in_sizes, int n_in,
                              void* d_out, int out_size, void* d_ws, size_t ws_size,
                              hipStream_t stream) {
    const float* X = (const float*)d_in[0];   // [64,1152,8]
    const float* W = (const float*)d_in[1];   // [8,43,16]
    float* out = (float*)d_out;               // [64,43,16]
    int* cnt = (int*)d_ws;                                    // 2*64 counters
    float* part = (float*)((char*)d_ws + 4096);               // [2][64][4][PARTS]
    hipMemsetAsync(d_ws, 0, 512, stream);                     // zero counters every call
    hipLaunchKernelGGL(capsule_routing_kernel, dim3(NB*NSLICE), dim3(THREADS), 0, stream,
                       X, W, out, cnt, part);
}

// Round 6
// 26.761 us; speedup vs baseline: 5.0784x; 5.0784x over previous
//
#include <hip/hip_runtime.h>

#define EPS 1e-7f
#define NB 64
#define NI 1152
#define NJ 8
#define NK 43
#define NL 16
#define NSLICE 4
#define SLICE 288            // NI / NSLICE
#define THREADS 384
#define NKG 11               // groups of 4 k's (44 = NK+1 pad)
#define CPS 292              // float4 row stride for cP (288 + 4 pad)
#define GPS 33               // float row stride for Gp (odd -> conflict-free)
#define PARTS 344            // NK*NJ
#define WVSZ 352             // NJ*44

// ---------- common main phase: logits+softmax (A), register-blocked G (B) ----------
__device__ __forceinline__ void routing_main(
    int tid, const float4* __restrict__ sXa, const float4* __restrict__ sXb,
    const float (* __restrict__ sWv)[44], float4* __restrict__ cP,
    float* __restrict__ gpOut)
{
    // ---- Phase A: logits + softmax for this slice's 288 i's ----
    float a[44];
    if (tid < SLICE) {
        float4 x0 = sXa[tid], x1 = sXb[tid];
        float xr[NJ] = {x0.x, x0.y, x0.z, x0.w, x1.x, x1.y, x1.z, x1.w};
        #pragma unroll
        for (int k = 0; k < 44; ++k) a[k] = 0.f;
        #pragma unroll
        for (int j = 0; j < NJ; ++j) {
            #pragma unroll
            for (int k4 = 0; k4 < NKG; ++k4) {
                float4 wv = *(const float4*)&sWv[j][k4*4];
                a[k4*4+0] = fmaf(xr[j], wv.x, a[k4*4+0]);
                a[k4*4+1] = fmaf(xr[j], wv.y, a[k4*4+1]);
                a[k4*4+2] = fmaf(xr[j], wv.z, a[k4*4+2]);
                a[k4*4+3] = fmaf(xr[j], wv.w, a[k4*4+3]);
            }
        }
        float m0=a[0], m1=a[1], m2=a[2], m3=a[3];
        #pragma unroll
        for (int k = 4; k < 40; k += 4) {
            m0 = fmaxf(m0, a[k+0]); m1 = fmaxf(m1, a[k+1]);
            m2 = fmaxf(m2, a[k+2]); m3 = fmaxf(m3, a[k+3]);
        }
        m0 = fmaxf(m0, a[40]); m1 = fmaxf(m1, a[41]); m2 = fmaxf(m2, a[42]);
        const float m = fmaxf(fmaxf(m0, m1), fmaxf(m2, m3));
        float z0=0.f, z1=0.f, z2=0.f, z3=0.f;
        #pragma unroll
        for (int k = 0; k < 40; k += 4) {
            a[k+0] = __expf(a[k+0]-m); z0 += a[k+0];
            a[k+1] = __expf(a[k+1]-m); z1 += a[k+1];
            a[k+2] = __expf(a[k+2]-m); z2 += a[k+2];
            a[k+3] = __expf(a[k+3]-m); z3 += a[k+3];
        }
        a[40] = __expf(a[40]-m); z0 += a[40];
        a[41] = __expf(a[41]-m); z1 += a[41];
        a[42] = __expf(a[42]-m); z2 += a[42];
        const float inv = 1.f / ((z0+z1) + (z2+z3));
        #pragma unroll
        for (int k = 0; k < NK; ++k) a[k] *= inv;
        a[43] = 0.f;
        #pragma unroll
        for (int kg = 0; kg < NKG; ++kg)
            cP[kg*CPS + tid] = make_float4(a[4*kg], a[4*kg+1], a[4*kg+2], a[4*kg+3]);
    }
    __syncthreads();   // cP ready
    // ---- Phase B: register-blocked G (352 threads, 9 iters) ----
    float acc[4][8];
    #pragma unroll
    for (int q = 0; q < 4; ++q)
        #pragma unroll
        for (int j = 0; j < 8; ++j) acc[q][j] = 0.f;
    if (tid < 352) {
        const int kg = tid >> 5, s = tid & 31;
        #pragma unroll
        for (int ii = 0; ii < SLICE/32; ++ii) {
            const int il = s + 32*ii;
            float4 c4 = cP[kg*CPS + il];
            float4 xa = sXa[il], xb = sXb[il];
            acc[0][0]=fmaf(c4.x,xa.x,acc[0][0]); acc[0][1]=fmaf(c4.x,xa.y,acc[0][1]);
            acc[0][2]=fmaf(c4.x,xa.z,acc[0][2]); acc[0][3]=fmaf(c4.x,xa.w,acc[0][3]);
            acc[0][4]=fmaf(c4.x,xb.x,acc[0][4]); acc[0][5]=fmaf(c4.x,xb.y,acc[0][5]);
            acc[0][6]=fmaf(c4.x,xb.z,acc[0][6]); acc[0][7]=fmaf(c4.x,xb.w,acc[0][7]);
            acc[1][0]=fmaf(c4.y,xa.x,acc[1][0]); acc[1][1]=fmaf(c4.y,xa.y,acc[1][1]);
            acc[1][2]=fmaf(c4.y,xa.z,acc[1][2]); acc[1][3]=fmaf(c4.y,xa.w,acc[1][3]);
            acc[1][4]=fmaf(c4.y,xb.x,acc[1][4]); acc[1][5]=fmaf(c4.y,xb.y,acc[1][5]);
            acc[1][6]=fmaf(c4.y,xb.z,acc[1][6]); acc[1][7]=fmaf(c4.y,xb.w,acc[1][7]);
            acc[2][0]=fmaf(c4.z,xa.x,acc[2][0]); acc[2][1]=fmaf(c4.z,xa.y,acc[2][1]);
            acc[2][2]=fmaf(c4.z,xa.z,acc[2][2]); acc[2][3]=fmaf(c4.z,xa.w,acc[2][3]);
            acc[2][4]=fmaf(c4.z,xb.x,acc[2][4]); acc[2][5]=fmaf(c4.z,xb.y,acc[2][5]);
            acc[2][6]=fmaf(c4.z,xb.z,acc[2][6]); acc[2][7]=fmaf(c4.z,xb.w,acc[2][7]);
            acc[3][0]=fmaf(c4.w,xa.x,acc[3][0]); acc[3][1]=fmaf(c4.w,xa.y,acc[3][1]);
            acc[3][2]=fmaf(c4.w,xa.z,acc[3][2]); acc[3][3]=fmaf(c4.w,xa.w,acc[3][3]);
            acc[3][4]=fmaf(c4.w,xb.x,acc[3][4]); acc[3][5]=fmaf(c4.w,xb.y,acc[3][5]);
            acc[3][6]=fmaf(c4.w,xb.z,acc[3][6]); acc[3][7]=fmaf(c4.w,xb.w,acc[3][7]);
        }
    }
    __syncthreads();   // cP reads done -> alias region as Gp
    float* Gp = (float*)cP;
    if (tid < 352) {
        #pragma unroll
        for (int q = 0; q < 4; ++q)
            #pragma unroll
            for (int j = 0; j < 8; ++j)
                Gp[tid*GPS + q*8 + j] = acc[q][j];
    }
    __syncthreads();
    // ---- reduce 32 lanes -> this slice's G partial -> global ws ----
    if (tid < PARTS) {
        const int k = tid >> 3, j = tid & 7;
        const int kg = k >> 2, k4 = k & 3;
        float g = 0.f;
        #pragma unroll 8
        for (int s = 0; s < 32; ++s) g += Gp[(kg*32 + s)*GPS + k4*8 + j];
        gpOut[tid] = g;
    }
}

// ---------- helpers ----------
__device__ __forceinline__ void load_slice(int tid, const float* Xb, int sl,
                                           float4* sXa, float4* sXb) {
    const float4* Xs4 = (const float4*)(Xb + (size_t)sl*SLICE*NJ);
    for (int t = tid; t < SLICE*2; t += THREADS) {
        float4 v = Xs4[t];
        if (t & 1) sXb[t >> 1] = v; else sXa[t >> 1] = v;
    }
}

__device__ __forceinline__ void squash_block(int tid, const float (*sS)[NL], float (*sV)[NL]) {
    if (tid < NK) {
        float s2 = 0.f;
        #pragma unroll
        for (int l = 0; l < NL; ++l) { float v = sS[tid][l]; s2 += v*v; }
        float scale = s2 / ((1.f + s2) * sqrtf(s2 + EPS));
        #pragma unroll
        for (int l = 0; l < NL; ++l) sV[tid][l] = scale * sS[tid][l];
    }
}

// ---------- K1: prologue (xs->v0->Wv0) + pass-1 main ----------
__global__ __launch_bounds__(THREADS, 1)
void caps_k1(const float* __restrict__ X, const float* __restrict__ W,
             float* __restrict__ wv0, float* __restrict__ gp1) {
    __shared__ __align__(16) float4 sXa[SLICE], sXb[SLICE];
    __shared__ __align__(16) float4 cP[NKG*CPS];
    __shared__ __align__(16) float sWv[NJ][44];
    __shared__ __align__(16) float sS[NK][NL];
    __shared__ __align__(16) float sV[NK][NL];
    __shared__ float sXs[NJ];

    const int tid = threadIdx.x;
    const int b  = blockIdx.x >> 2;
    const int sl = blockIdx.x & 3;
    const float* Xb = X + (size_t)b * (NI*NJ);

    load_slice(tid, Xb, sl, sXa, sXb);
    // xs[j] = sum over ALL i (redundant per block); scratch aliases cP
    {
        float* red = (float*)cP;
        const int j = tid / 48, sub = tid % 48;
        float p = 0.f;
        #pragma unroll
        for (int ii = 0; ii < NI/48; ++ii) p += Xb[(sub + 48*ii)*NJ + j];
        red[j*48 + sub] = p;
    }
    __syncthreads();
    if (tid < NJ) {
        const float* red = (const float*)cP;
        float s = 0.f;
        for (int q = 0; q < 48; ++q) s += red[tid*48 + q];
        sXs[tid] = s;
    }
    __syncthreads();
    // s0 = (1/43) * xs . W  (W from global/L2)
    for (int t = tid; t < NK*NL; t += THREADS) {
        float s = 0.f;
        #pragma unroll
        for (int j = 0; j < NJ; ++j) s += sXs[j] * W[j*NK*NL + t];
        sS[t >> 4][t & 15] = s * (1.0f/43.0f);
    }
    __syncthreads();
    squash_block(tid, sS, sV);
    __syncthreads();
    // Wv0[j,k]; sl==0 also persists it for K2
    if (tid < WVSZ) {
        const int j = tid / 44, k = tid % 44;
        float wv = 0.f;
        if (k < NK) {
            const float4* Wr = (const float4*)(W + j*NK*NL + k*NL);
            #pragma unroll
            for (int l4 = 0; l4 < 4; ++l4) {
                float4 w = Wr[l4];
                const float4 vv = *(const float4*)&sV[k][l4*4];
                wv += w.x*vv.x + w.y*vv.y + w.z*vv.z + w.w*vv.w;
            }
        }
        sWv[j][k] = wv;
        if (sl == 0) wv0[(size_t)b*WVSZ + tid] = wv;
    }
    __syncthreads();
    routing_main(tid, sXa, sXb, sWv, cP, gp1 + (size_t)(b*NSLICE + sl)*PARTS);
}

// ---------- K2: pass-1 tail (G1->v1->WvAcc) + pass-2 main ----------
__global__ __launch_bounds__(THREADS, 1)
void caps_k2(const float* __restrict__ X, const float* __restrict__ W,
             const float* __restrict__ wv0, const float* __restrict__ gp1,
             float* __restrict__ gp2) {
    __shared__ __align__(16) float4 sXa[SLICE], sXb[SLICE];
    __shared__ __align__(16) float4 cP[NKG*CPS];
    __shared__ __align__(16) float sWv[NJ][44];
    __shared__ __align__(16) float sS[NK][NL];
    __shared__ __align__(16) float sV[NK][NL];
    __shared__ float sG[PARTS];

    const int tid = threadIdx.x;
    const int b  = blockIdx.x >> 2;
    const int sl = blockIdx.x & 3;
    const float* Xb = X + (size_t)b * (NI*NJ);

    load_slice(tid, Xb, sl, sXa, sXb);
    // reduce GP1 -> G (redundant per block)
    if (tid < PARTS) {
        float g = 0.f;
        #pragma unroll
        for (int q = 0; q < NSLICE; ++q) g += gp1[(size_t)(b*NSLICE + q)*PARTS + tid];
        sG[tid] = g;
    }
    __syncthreads();
    // s1 = G . W
    for (int t = tid; t < NK*NL; t += THREADS) {
        const int k = t >> 4;
        float s = 0.f;
        #pragma unroll
        for (int j = 0; j < NJ; ++j) s = fmaf(sG[k*8+j], W[j*NK*NL + t], s);
        sS[k][t & 15] = s;
    }
    __syncthreads();
    squash_block(tid, sS, sV);
    __syncthreads();
    // WvAcc = Wv0 + Wv1
    if (tid < WVSZ) {
        const int j = tid / 44, k = tid % 44;
        float wv = 0.f;
        if (k < NK) {
            const float4* Wr = (const float4*)(W + j*NK*NL + k*NL);
            #pragma unroll
            for (int l4 = 0; l4 < 4; ++l4) {
                float4 w = Wr[l4];
                const float4 vv = *(const float4*)&sV[k][l4*4];
                wv += w.x*vv.x + w.y*vv.y + w.z*vv.z + w.w*vv.w;
            }
        }
        sWv[j][k] = wv0[(size_t)b*WVSZ + tid] + wv;
    }
    __syncthreads();
    routing_main(tid, sXa, sXb, sWv, cP, gp2 + (size_t)(b*NSLICE + sl)*PARTS);
}

// ---------- K3: pass-2 tail (G2 -> s -> squash -> out) ----------
__global__ __launch_bounds__(THREADS, 1)
void caps_k3(const float* __restrict__ W, const float* __restrict__ gp2,
             float* __restrict__ out) {
    __shared__ float sG[PARTS];
    __shared__ __align__(16) float sS[NK][NL];
    __shared__ __align__(16) float sV[NK][NL];
    const int tid = threadIdx.x;
    const int b = blockIdx.x;
    if (tid < PARTS) {
        float g = 0.f;
        #pragma unroll
        for (int q = 0; q < NSLICE; ++q) g += gp2[(size_t)(b*NSLICE + q)*PARTS + tid];
        sG[tid] = g;
    }
    __syncthreads();
    for (int t = tid; t < NK*NL; t += THREADS) {
        const int k = t >> 4;
        float s = 0.f;
        #pragma unroll
        for (int j = 0; j < NJ; ++j) s = fmaf(sG[k*8+j], W[j*NK*NL + t], s);
        sS[k][t & 15] = s;
    }
    __syncthreads();
    squash_block(tid, sS, sV);
    __syncthreads();
    for (int t = tid; t < NK*NL; t += THREADS)
        out[(size_t)b*NK*NL + t] = sV[t >> 4][t & 15];
}

extern "C" void kernel_launch(void* const* d_in, const int* in_sizes, int n_in,
                              void* d_out, int out_size, void* d_ws, size_t ws_size,
                              hipStream_t stream) {
    const float* X = (const float*)d_in[0];   // [64,1152,8]
    const float* W = (const float*)d_in[1];   // [8,43,16]
    float* out = (float*)d_out;               // [64,43,16]
    float* wv0 = (float*)d_ws;                // [64][352]
    float* gp1 = wv0 + NB*WVSZ;               // [64][4][344]
    float* gp2 = gp1 + NB*NSLICE*PARTS;       // [64][4][344]
    hipLaunchKernelGGL(caps_k1, dim3(NB*NSLICE), dim3(THREADS), 0, stream, X, W, wv0, gp1);
    hipLaunchKernelGGL(caps_k2, dim3(NB*NSLICE), dim3(THREADS), 0, stream, X, W, wv0, gp1, gp2);
    hipLaunchKernelGGL(caps_k3, dim3(NB), dim3(THREADS), 0, stream, W, gp2, out);
}

// Round 7
// 24.979 us; speedup vs baseline: 5.4407x; 1.0713x over previous
//
#include <hip/hip_runtime.h>

#define EPS 1e-7f
#define NB 64
#define NI 1152
#define NJ 8
#define NK 43
#define NL 16
#define KL (NK*NL)        // 688
#define NSLICE 8
#define SLICE 144         // NI / NSLICE
#define THREADS 384
#define NKG 11            // groups of 4 k's (44 = NK+1 pad)
#define CPS 148           // float4 row stride for cP (144 + 4 pad)
#define PARTS 344         // NK*NJ
#define WVSZ 352          // NJ*44
#define SVP 17            // sV padded row stride (floats, odd -> conflict-free)

// ---- load this block's 144-row X slice into two float4 planes ----
__device__ __forceinline__ void load_slice(int tid, const float* __restrict__ Xb, int sl,
                                           float4* sXa, float4* sXb) {
    if (tid < SLICE*2) {
        const float4* Xs4 = (const float4*)(Xb + (size_t)sl*SLICE*NJ);
        float4 v = Xs4[tid];
        if (tid & 1) sXb[tid >> 1] = v; else sXa[tid >> 1] = v;
    }
}

// ---- fused squash: given s-value for (k,l) laid out in 16-aligned lane groups,
//      returns scale[k]*sv via intra-group shuffle reduction of sum(s^2) ----
__device__ __forceinline__ float squash_scale(float sv) {
    float sq = sv * sv;
    sq += __shfl_xor(sq, 1);
    sq += __shfl_xor(sq, 2);
    sq += __shfl_xor(sq, 4);
    sq += __shfl_xor(sq, 8);
    const float scale = sq / ((1.f + sq) * sqrtf(sq + EPS));
    return scale * sv;
}

// ---- main phase: per-i softmax (A) then register-blocked G + shuffle reduce (B) ----
__device__ __forceinline__ void routing_main(
    int tid, const float4* sXa, const float4* sXb,
    const float (*sWv)[44], float4* cP, float* __restrict__ gpOut)
{
    // Phase A: logits + softmax for this slice's 144 i's (one i per thread)
    if (tid < SLICE) {
        float4 x0 = sXa[tid], x1 = sXb[tid];
        float xr[NJ] = {x0.x, x0.y, x0.z, x0.w, x1.x, x1.y, x1.z, x1.w};
        float a[44];
        #pragma unroll
        for (int k = 0; k < 44; ++k) a[k] = 0.f;
        #pragma unroll
        for (int j = 0; j < NJ; ++j) {
            #pragma unroll
            for (int k4 = 0; k4 < NKG; ++k4) {
                float4 wv = *(const float4*)&sWv[j][k4*4];
                a[k4*4+0] = fmaf(xr[j], wv.x, a[k4*4+0]);
                a[k4*4+1] = fmaf(xr[j], wv.y, a[k4*4+1]);
                a[k4*4+2] = fmaf(xr[j], wv.z, a[k4*4+2]);
                a[k4*4+3] = fmaf(xr[j], wv.w, a[k4*4+3]);
            }
        }
        float m0=a[0], m1=a[1], m2=a[2], m3=a[3];
        #pragma unroll
        for (int k = 4; k < 40; k += 4) {
            m0 = fmaxf(m0, a[k+0]); m1 = fmaxf(m1, a[k+1]);
            m2 = fmaxf(m2, a[k+2]); m3 = fmaxf(m3, a[k+3]);
        }
        m0 = fmaxf(m0, a[40]); m1 = fmaxf(m1, a[41]); m2 = fmaxf(m2, a[42]);
        const float m = fmaxf(fmaxf(m0, m1), fmaxf(m2, m3));
        float z0=0.f, z1=0.f, z2=0.f, z3=0.f;
        #pragma unroll
        for (int k = 0; k < 40; k += 4) {
            a[k+0] = __expf(a[k+0]-m); z0 += a[k+0];
            a[k+1] = __expf(a[k+1]-m); z1 += a[k+1];
            a[k+2] = __expf(a[k+2]-m); z2 += a[k+2];
            a[k+3] = __expf(a[k+3]-m); z3 += a[k+3];
        }
        a[40] = __expf(a[40]-m); z0 += a[40];
        a[41] = __expf(a[41]-m); z1 += a[41];
        a[42] = __expf(a[42]-m); z2 += a[42];
        const float inv = 1.f / ((z0+z1) + (z2+z3));
        #pragma unroll
        for (int k = 0; k < NK; ++k) a[k] *= inv;
        a[43] = 0.f;
        #pragma unroll
        for (int kg = 0; kg < NKG; ++kg)
            cP[kg*CPS + tid] = make_float4(a[4*kg], a[4*kg+1], a[4*kg+2], a[4*kg+3]);
    }
    __syncthreads();   // cP ready
    // Phase B: 11 k-groups x 16 lanes; 9 i's per lane; reduce via butterfly
    if (tid < NKG*16) {
        const int kg = tid >> 4, s = tid & 15;
        float acc[4][8];
        #pragma unroll
        for (int q = 0; q < 4; ++q)
            #pragma unroll
            for (int j = 0; j < 8; ++j) acc[q][j] = 0.f;
        #pragma unroll
        for (int ii = 0; ii < SLICE/16; ++ii) {
            const int il = s + 16*ii;
            float4 c4 = cP[kg*CPS + il];
            float4 xa = sXa[il], xb = sXb[il];
            acc[0][0]=fmaf(c4.x,xa.x,acc[0][0]); acc[0][1]=fmaf(c4.x,xa.y,acc[0][1]);
            acc[0][2]=fmaf(c4.x,xa.z,acc[0][2]); acc[0][3]=fmaf(c4.x,xa.w,acc[0][3]);
            acc[0][4]=fmaf(c4.x,xb.x,acc[0][4]); acc[0][5]=fmaf(c4.x,xb.y,acc[0][5]);
            acc[0][6]=fmaf(c4.x,xb.z,acc[0][6]); acc[0][7]=fmaf(c4.x,xb.w,acc[0][7]);
            acc[1][0]=fmaf(c4.y,xa.x,acc[1][0]); acc[1][1]=fmaf(c4.y,xa.y,acc[1][1]);
            acc[1][2]=fmaf(c4.y,xa.z,acc[1][2]); acc[1][3]=fmaf(c4.y,xa.w,acc[1][3]);
            acc[1][4]=fmaf(c4.y,xb.x,acc[1][4]); acc[1][5]=fmaf(c4.y,xb.y,acc[1][5]);
            acc[1][6]=fmaf(c4.y,xb.z,acc[1][6]); acc[1][7]=fmaf(c4.y,xb.w,acc[1][7]);
            acc[2][0]=fmaf(c4.z,xa.x,acc[2][0]); acc[2][1]=fmaf(c4.z,xa.y,acc[2][1]);
            acc[2][2]=fmaf(c4.z,xa.z,acc[2][2]); acc[2][3]=fmaf(c4.z,xa.w,acc[2][3]);
            acc[2][4]=fmaf(c4.z,xb.x,acc[2][4]); acc[2][5]=fmaf(c4.z,xb.y,acc[2][5]);
            acc[2][6]=fmaf(c4.z,xb.z,acc[2][6]); acc[2][7]=fmaf(c4.z,xb.w,acc[2][7]);
            acc[3][0]=fmaf(c4.w,xa.x,acc[3][0]); acc[3][1]=fmaf(c4.w,xa.y,acc[3][1]);
            acc[3][2]=fmaf(c4.w,xa.z,acc[3][2]); acc[3][3]=fmaf(c4.w,xa.w,acc[3][3]);
            acc[3][4]=fmaf(c4.w,xb.x,acc[3][4]); acc[3][5]=fmaf(c4.w,xb.y,acc[3][5]);
            acc[3][6]=fmaf(c4.w,xb.z,acc[3][6]); acc[3][7]=fmaf(c4.w,xb.w,acc[3][7]);
        }
        // butterfly reduce across the 16 lanes: lane s ends with G for v=2s,2s+1
        float cur[32];
        #pragma unroll
        for (int q = 0; q < 4; ++q)
            #pragma unroll
            for (int j = 0; j < 8; ++j) cur[q*8+j] = acc[q][j];
        {   const bool up = (tid & 8) != 0;
            #pragma unroll
            for (int v = 0; v < 16; ++v) {
                float give = up ? cur[v] : cur[v+16];
                float keep = up ? cur[v+16] : cur[v];
                cur[v] = keep + __shfl_xor(give, 8);
            } }
        {   const bool up = (tid & 4) != 0;
            #pragma unroll
            for (int v = 0; v < 8; ++v) {
                float give = up ? cur[v] : cur[v+8];
                float keep = up ? cur[v+8] : cur[v];
                cur[v] = keep + __shfl_xor(give, 4);
            } }
        {   const bool up = (tid & 2) != 0;
            #pragma unroll
            for (int v = 0; v < 4; ++v) {
                float give = up ? cur[v] : cur[v+4];
                float keep = up ? cur[v+4] : cur[v];
                cur[v] = keep + __shfl_xor(give, 2);
            } }
        {   const bool up = (tid & 1) != 0;
            #pragma unroll
            for (int v = 0; v < 2; ++v) {
                float give = up ? cur[v] : cur[v+2];
                float keep = up ? cur[v+2] : cur[v];
                cur[v] = keep + __shfl_xor(give, 1);
            } }
        const int p = kg*32 + (s << 1);   // = k*8+j for v=2s
        if (p < PARTS)
            *(float2*)&gpOut[p] = make_float2(cur[0], cur[1]);
    }
}

// ---------- K1: prologue (xs->v0->Wv0) + pass-1 main ----------
__global__ __launch_bounds__(THREADS, 3)
void caps_k1(const float* __restrict__ X, const float* __restrict__ W,
             float* __restrict__ wv0g, float* __restrict__ gp1) {
    __shared__ __align__(16) float4 sXa[SLICE], sXb[SLICE];
    __shared__ __align__(16) float4 cP[NKG*CPS];
    __shared__ __align__(16) float sWv[NJ][44];
    __shared__ __align__(16) float sV[NK*SVP];
    __shared__ __align__(16) float4 xsW[12];
    __shared__ float sXs[NJ];

    const int tid = threadIdx.x;
    const int b  = blockIdx.x >> 3;
    const int sl = blockIdx.x & 7;
    const float* Xb = X + (size_t)b * (NI*NJ);

    load_slice(tid, Xb, sl, sXa, sXb);
    // xs: coalesced float4 accumulation over full X (even tid: j0-3, odd tid: j4-7)
    {
        const float4* X4 = (const float4*)Xb;
        float4 ax = X4[tid];
        #pragma unroll
        for (int r = 1; r < 6; ++r) {
            float4 v = X4[tid + r*THREADS];
            ax.x += v.x; ax.y += v.y; ax.z += v.z; ax.w += v.w;
        }
        #pragma unroll
        for (int msk = 2; msk <= 32; msk <<= 1) {
            ax.x += __shfl_xor(ax.x, msk);
            ax.y += __shfl_xor(ax.y, msk);
            ax.z += __shfl_xor(ax.z, msk);
            ax.w += __shfl_xor(ax.w, msk);
        }
        if ((tid & 63) < 2) xsW[(tid >> 6)*2 + (tid & 1)] = ax;
    }
    __syncthreads();
    if (tid < NJ) {
        const float* f = (const float*)xsW;
        float s = 0.f;
        #pragma unroll
        for (int w = 0; w < 6; ++w) s += f[(w*2 + (tid >> 2))*4 + (tid & 3)];
        sXs[tid] = s;
    }
    __syncthreads();
    // fused s0 -> squash -> v0
    for (int t = tid; t < KL; t += THREADS) {
        float sv = 0.f;
        #pragma unroll
        for (int j = 0; j < NJ; ++j) sv = fmaf(sXs[j], W[j*KL + t], sv);
        sv *= (1.0f/43.0f);
        sV[(t >> 4)*SVP + (t & 15)] = squash_scale(sv);
    }
    __syncthreads();
    // Wv0[j,k]; slice 0 persists for K2
    if (tid < WVSZ) {
        const int j = tid / 44, k = tid % 44;
        float wv = 0.f;
        if (k < NK) {
            #pragma unroll
            for (int l = 0; l < NL; ++l)
                wv = fmaf(W[j*KL + k*NL + l], sV[k*SVP + l], wv);
        }
        ((float*)sWv)[tid] = wv;
        if (sl == 0) wv0g[(size_t)b*WVSZ + tid] = wv;
    }
    __syncthreads();
    routing_main(tid, sXa, sXb, sWv, cP, gp1 + (size_t)(b*NSLICE + sl)*PARTS);
}

// ---------- K2: pass-1 tail (G1->v1->WvAcc) + pass-2 main ----------
__global__ __launch_bounds__(THREADS, 3)
void caps_k2(const float* __restrict__ X, const float* __restrict__ W,
             const float* __restrict__ wv0g, const float* __restrict__ gp1,
             float* __restrict__ gp2) {
    __shared__ __align__(16) float4 sXa[SLICE], sXb[SLICE];
    __shared__ __align__(16) float4 cP[NKG*CPS];
    __shared__ __align__(16) float sWv[NJ][44];
    __shared__ __align__(16) float sV[NK*SVP];
    __shared__ float sG[PARTS];

    const int tid = threadIdx.x;
    const int b  = blockIdx.x >> 3;
    const int sl = blockIdx.x & 7;
    const float* Xb = X + (size_t)b * (NI*NJ);

    load_slice(tid, Xb, sl, sXa, sXb);
    if (tid < PARTS) {
        float g = 0.f;
        #pragma unroll
        for (int q = 0; q < NSLICE; ++q) g += gp1[(size_t)(b*NSLICE + q)*PARTS + tid];
        sG[tid] = g;
    }
    __syncthreads();
    // fused s1 -> squash -> v1
    for (int t = tid; t < KL; t += THREADS) {
        const int k8 = (t >> 4)*8;
        float sv = 0.f;
        #pragma unroll
        for (int j = 0; j < NJ; ++j) sv = fmaf(sG[k8 + j], W[j*KL + t], sv);
        sV[(t >> 4)*SVP + (t & 15)] = squash_scale(sv);
    }
    __syncthreads();
    // WvAcc = Wv0 + Wv1
    if (tid < WVSZ) {
        const int j = tid / 44, k = tid % 44;
        float wv = 0.f;
        if (k < NK) {
            #pragma unroll
            for (int l = 0; l < NL; ++l)
                wv = fmaf(W[j*KL + k*NL + l], sV[k*SVP + l], wv);
        }
        ((float*)sWv)[tid] = wv0g[(size_t)b*WVSZ + tid] + wv;
    }
    __syncthreads();
    routing_main(tid, sXa, sXb, sWv, cP, gp2 + (size_t)(b*NSLICE + sl)*PARTS);
}

// ---------- K3: pass-2 tail (G2 -> s -> squash -> out), one barrier ----------
__global__ __launch_bounds__(THREADS, 1)
void caps_k3(const float* __restrict__ W, const float* __restrict__ gp2,
             float* __restrict__ out) {
    __shared__ float sG[PARTS];
    const int tid = threadIdx.x;
    const int b = blockIdx.x;
    if (tid < PARTS) {
        float g = 0.f;
        #pragma unroll
        for (int q = 0; q < NSLICE; ++q) g += gp2[(size_t)(b*NSLICE + q)*PARTS + tid];
        sG[tid] = g;
    }
    __syncthreads();
    for (int t = tid; t < KL; t += THREADS) {
        const int k8 = (t >> 4)*8;
        float sv = 0.f;
        #pragma unroll
        for (int j = 0; j < NJ; ++j) sv = fmaf(sG[k8 + j], W[j*KL + t], sv);
        out[(size_t)b*KL + t] = squash_scale(sv);
    }
}

extern "C" void kernel_launch(void* const* d_in, const int* in_sizes, int n_in,
                              void* d_out, int out_size, void* d_ws, size_t ws_size,
                              hipStream_t stream) {
    const float* X = (const float*)d_in[0];   // [64,1152,8]
    const float* W = (const float*)d_in[1];   // [8,43,16]
    float* out = (float*)d_out;               // [64,43,16]
    float* wv0 = (float*)d_ws;                // [64][352]
    float* gp1 = wv0 + NB*WVSZ;               // [64][8][344]
    float* gp2 = gp1 + NB*NSLICE*PARTS;       // [64][8][344]
    hipLaunchKernelGGL(caps_k1, dim3(NB*NSLICE), dim3(THREADS), 0, stream, X, W, wv0, gp1);
    hipLaunchKernelGGL(caps_k2, dim3(NB*NSLICE), dim3(THREADS), 0, stream, X, W, wv0, gp1, gp2);
    hipLaunchKernelGGL(caps_k3, dim3(NB), dim3(THREADS), 0, stream, W, gp2, out);
}